// Round 2
// baseline (2762.571 us; speedup 1.0000x reference)
//
#include <hip/hip_runtime.h>
#include <cstdint>
#include <cstddef>

#define BB 8
#define SS 2
#define TT 512
#define CC 2048
#define ND 1024
#define AD 16384
#define NN 256
#define AN 2048
#define NEGV -1e30f

// orderable-uint encoding of float for atomicMax
__device__ __forceinline__ unsigned encf(float f) {
    unsigned u = __float_as_uint(f);
    return (u & 0x80000000u) ? ~u : (u | 0x80000000u);
}
__device__ __forceinline__ float decf(unsigned k) {
    unsigned u = (k & 0x80000000u) ? (k ^ 0x80000000u) : ~k;
    return __uint_as_float(u);
}
#define ENC_NEGINF 0x007FFFFFu   // encf(-inf)

// ---------------------------------------------------------------------------
// prep: per-graph counting sort of arcs by dst. Output record packs all three
// indices into one u32: src | pdf<<10 | dst<<21  (src<1024, pdf<2048, dst<1024)
// One block per graph, blockDim.x == N (power of 2).
// ---------------------------------------------------------------------------
__global__ void prep_kernel(const int* __restrict__ src, const int* __restrict__ dst,
                            const int* __restrict__ pdf, const float* __restrict__ w,
                            uint2* __restrict__ arcs, int N, int A)
{
    __shared__ int cnt[1024];
    __shared__ int pos[1024];
    const int g = blockIdx.x;
    src += (size_t)g * A; dst += (size_t)g * A; pdf += (size_t)g * A; w += (size_t)g * A;
    arcs += (size_t)g * A;
    const int tid = threadIdx.x;
    cnt[tid] = 0;
    __syncthreads();
    for (int a = tid; a < A; a += blockDim.x) atomicAdd(&cnt[dst[a]], 1);
    __syncthreads();
    const int deg = cnt[tid];
    pos[tid] = deg;
    __syncthreads();
    for (int off = 1; off < blockDim.x; off <<= 1) {
        int add = (tid >= off) ? pos[tid - off] : 0;
        __syncthreads();
        pos[tid] += add;
        __syncthreads();
    }
    const int excl = pos[tid] - deg;
    cnt[tid] = excl;
    __syncthreads();
    for (int a = tid; a < A; a += blockDim.x) {
        const int d2 = dst[a];
        const int p2 = atomicAdd(&cnt[d2], 1);
        arcs[p2] = make_uint2((unsigned)src[a] | ((unsigned)pdf[a] << 10) |
                              ((unsigned)d2 << 21),
                              __float_as_uint(w[a]));
    }
}

// ---------------------------------------------------------------------------
// FSM forward, balanced arcs-per-thread version.
// Thread tid owns arcs [tid*APT, tid*APT+APT) (sorted by dst, held in regs)
// and state tid (tid < NST). Per step:
//   Phase A: scores -> per-run local max -> atomicMax(u32-encoded) per run
//   Phase B: per-run read clamped max, sum exp(sc - mc), ds_add_f32 per run
//   Epilogue: owner applies reference fixup, resets slots.
// ---------------------------------------------------------------------------
template<int APT, int NST>
__device__ void fsm_forward(const float* __restrict__ rowbase, int L,
    const uint2* __restrict__ arcs_g,
    const float* __restrict__ initv, const float* __restrict__ finalv,
    float* __restrict__ res,
    float* llh0, float* llh1, float* alpha_s, unsigned* mslot, float* sslot)
{
    const int tid = threadIdx.x;
    uint2 arc[APT];
    #pragma unroll
    for (int k = 0; k < APT; ++k) arc[k] = arcs_g[tid * APT + k];
    const bool st = tid < NST;
    float fin = 0.f;
    if (st) {
        alpha_s[tid] = initv[tid];
        mslot[tid] = ENC_NEGINF;
        sslot[tid] = 0.f;
        fin = finalv[tid];
    }
    if (L > 0) {
        llh0[tid]        = rowbase[tid];
        llh0[tid + 1024] = rowbase[tid + 1024];
    }
    __syncthreads();

    for (int t = 0; t < L; ++t) {
        float* cur = (t & 1) ? llh1 : llh0;
        float* nxt = (t & 1) ? llh0 : llh1;
        const bool pre = (t + 1 < L);
        float p0 = 0.f, p1 = 0.f;
        if (pre) {
            const float* nb = rowbase + (size_t)(t + 1) * CC;
            p0 = nb[tid];
            p1 = nb[tid + 1024];
        }
        // ---- Phase A: scores + per-run max -> atomicMax
        float sc[APT];
        unsigned rd = 0xffffffffu;
        float rmax = -INFINITY;
        #pragma unroll
        for (int k = 0; k < APT; ++k) {
            const unsigned x = arc[k].x;
            const int srcI = (int)(x & 1023u);
            const int pdfI = (int)((x >> 10) & 2047u);
            const unsigned dstI = x >> 21;
            const float s = alpha_s[srcI] + __uint_as_float(arc[k].y) + cur[pdfI];
            sc[k] = s;
            if (dstI == rd) {
                rmax = fmaxf(rmax, s);
            } else {
                if (rd != 0xffffffffu) atomicMax(&mslot[rd], encf(rmax));
                rd = dstI;
                rmax = s;
            }
        }
        if (rd != 0xffffffffu) atomicMax(&mslot[rd], encf(rmax));
        __syncthreads();
        // ---- Phase B: per-run clamped max, exp-sum, ds_add_f32
        rd = 0xffffffffu;
        float racc = 0.f, rmc = 0.f;
        #pragma unroll
        for (int k = 0; k < APT; ++k) {
            const unsigned dstI = arc[k].x >> 21;
            if (dstI != rd) {
                if (rd != 0xffffffffu) atomicAdd(&sslot[rd], racc);
                rd = dstI;
                rmc = fmaxf(decf(mslot[rd]), NEGV);
                racc = 0.f;
            }
            racc += __expf(sc[k] - rmc);
        }
        if (rd != 0xffffffffu) atomicAdd(&sslot[rd], racc);
        __syncthreads();
        // ---- Epilogue (owner thread per state)
        if (st) {
            const float m  = decf(mslot[tid]);
            const float mc = fmaxf(m, NEGV);
            const float s  = sslot[tid];
            alpha_s[tid] = mc + __logf(fmaxf(s, 1e-30f));
            mslot[tid] = ENC_NEGINF;
            sslot[tid] = 0.f;
        }
        if (pre) { nxt[tid] = p0; nxt[tid + 1024] = p1; }
        __syncthreads();
    }

    // logsumexp(alpha + final), block-wide tree reduce in llh0
    const float v = st ? (alpha_s[tid] + fin) : -INFINITY;
    float* red = llh0;
    red[tid] = v;
    __syncthreads();
    for (int off = 512; off > 0; off >>= 1) {
        if (tid < off) red[tid] = fmaxf(red[tid], red[tid + off]);
        __syncthreads();
    }
    const float M = red[0];
    __syncthreads();
    red[tid] = __expf(v - M);
    __syncthreads();
    for (int off = 512; off > 0; off >>= 1) {
        if (tid < off) red[tid] += red[tid + off];
        __syncthreads();
    }
    if (tid == 0) *res = M + __logf(red[0]);
}

__global__ __launch_bounds__(1024) void fwd_kernel(
    const float* __restrict__ est, const int* __restrict__ seqlen,
    const uint2* __restrict__ den_arcs,
    const float* __restrict__ den_init, const float* __restrict__ den_final,
    const uint2* __restrict__ num_arcs,
    const float* __restrict__ num_init, const float* __restrict__ num_final,
    float* __restrict__ res)
{
    __shared__ float llh0[2048];
    __shared__ float llh1[2048];
    __shared__ float alpha[1024];
    __shared__ unsigned mslot[1024];
    __shared__ float sslot[1024];
    const int bid = blockIdx.x;
    if (bid < 16) {
        const int s = bid >> 3, b = bid & 7;
        const float* rowbase = est + (size_t)(b * SS + s) * TT * CC;
        const int L = seqlen[b * SS + s];
        fsm_forward<16, ND>(rowbase, L, den_arcs, den_init, den_final,
                            &res[bid], llh0, llh1, alpha, mslot, sslot);
    } else {
        const int q = bid - 16;
        const int p = q >> 4, g = q & 15;
        const int s = g >> 3, b = g & 7;
        const int sp = p ? (1 - s) : s;
        const float* rowbase = est + (size_t)(b * SS + sp) * TT * CC;
        const int L = seqlen[b * SS + sp];
        fsm_forward<2, NN>(rowbase, L,
                           num_arcs + (size_t)g * AN,
                           num_init + (size_t)g * NN, num_final + (size_t)g * NN,
                           &res[16 + p * 16 + g], llh0, llh1, alpha, mslot, sslot);
    }
}

// res layout: [0..15] den (s*8+b), [16..31] num perm0, [32..47] num perm1
__global__ void finalize_kernel(const float* __restrict__ res, float* __restrict__ out)
{
    if (threadIdx.x == 0 && blockIdx.x == 0) {
        float loss = 0.f;
        for (int b = 0; b < BB; ++b) {
            const float den = res[b] + res[8 + b];
            const float n0  = res[16 + b] + res[16 + 8 + b];
            const float n1  = res[32 + b] + res[32 + 8 + b];
            const float nm  = fminf(n0, n1);
            loss += -(nm - den);
        }
        out[0] = loss;
    }
}

extern "C" void kernel_launch(void* const* d_in, const int* in_sizes, int n_in,
                              void* d_out, int out_size, void* d_ws, size_t ws_size,
                              hipStream_t stream)
{
    const float* est       = (const float*)d_in[0];
    const int*   seqlen    = (const int*)  d_in[1];
    const int*   den_src   = (const int*)  d_in[2];
    const int*   den_dst   = (const int*)  d_in[3];
    const int*   den_pdf   = (const int*)  d_in[4];
    const float* den_w     = (const float*)d_in[5];
    const float* den_init  = (const float*)d_in[6];
    const float* den_final = (const float*)d_in[7];
    const int*   num_src   = (const int*)  d_in[8];
    const int*   num_dst   = (const int*)  d_in[9];
    const int*   num_pdf   = (const int*)  d_in[10];
    const float* num_w     = (const float*)d_in[11];
    const float* num_init  = (const float*)d_in[12];
    const float* num_final = (const float*)d_in[13];

    char* ws = (char*)d_ws;
    uint2* den_arcs = (uint2*)(ws + 0);        // 131072 B
    uint2* num_arcs = (uint2*)(ws + 131072);   // 262144 B -> end 393216
    float* res      = (float*)(ws + 393216);   // 192 B

    prep_kernel<<<1, 1024, 0, stream>>>(den_src, den_dst, den_pdf, den_w,
                                        den_arcs, ND, AD);
    prep_kernel<<<16, 256, 0, stream>>>(num_src, num_dst, num_pdf, num_w,
                                        num_arcs, NN, AN);

    fwd_kernel<<<48, 1024, 0, stream>>>(est, seqlen,
                                        den_arcs, den_init, den_final,
                                        num_arcs, num_init, num_final, res);

    finalize_kernel<<<1, 64, 0, stream>>>(res, (float*)d_out);
}

// Round 3
// 2182.281 us; speedup vs baseline: 1.2659x; 1.2659x over previous
//
#include <hip/hip_runtime.h>
#include <cstdint>
#include <cstddef>

#define BB 8
#define SS 2
#define TT 512
#define CC 2048
#define ND 1024
#define AD 16384
#define NN 256
#define AN 2048

// ---------------------------------------------------------------------------
// prep: per-graph counting sort of arcs by dst. Record packs indices into one
// u32: src | pdf<<10 | dst<<21 (src<1024, pdf<2048, dst<1024); payload .y is
// exp(weight) (linear-space arc factor). One block per graph, blockDim.x == N.
// ---------------------------------------------------------------------------
__global__ void prep_kernel(const int* __restrict__ src, const int* __restrict__ dst,
                            const int* __restrict__ pdf, const float* __restrict__ w,
                            uint2* __restrict__ arcs, int N, int A)
{
    __shared__ int cnt[1024];
    __shared__ int pos[1024];
    const int g = blockIdx.x;
    src += (size_t)g * A; dst += (size_t)g * A; pdf += (size_t)g * A; w += (size_t)g * A;
    arcs += (size_t)g * A;
    const int tid = threadIdx.x;
    cnt[tid] = 0;
    __syncthreads();
    for (int a = tid; a < A; a += blockDim.x) atomicAdd(&cnt[dst[a]], 1);
    __syncthreads();
    const int deg = cnt[tid];
    pos[tid] = deg;
    __syncthreads();
    for (int off = 1; off < blockDim.x; off <<= 1) {
        int add = (tid >= off) ? pos[tid - off] : 0;
        __syncthreads();
        pos[tid] += add;
        __syncthreads();
    }
    const int excl = pos[tid] - deg;
    cnt[tid] = excl;
    __syncthreads();
    for (int a = tid; a < A; a += blockDim.x) {
        const int d2 = dst[a];
        const int p2 = atomicAdd(&cnt[d2], 1);
        arcs[p2] = make_uint2((unsigned)src[a] | ((unsigned)pdf[a] << 10) |
                              ((unsigned)d2 << 21),
                              __float_as_uint(__expf(w[a])));
    }
}

// ---------------------------------------------------------------------------
// Linear-space FSM forward with per-step max-renormalization.
//   beta'[j] = sum_{arcs a: dst=j} beta[src_a] * e^{w_a} * e^{llh_t[pdf_a]}
//   after each step: m = max_j beta'[j]; beta <- beta'/m; S += log m.
// alpha_t[j] == S + log(beta[j]) exactly (max term of each segment-logsumexp
// contributes >= its max, so the reference's NEG/1e-30 clamps never bind).
// TPB = 512. Thread owns arcs [tid*APT, (tid+1)*APT) sorted by dst (in regs)
// and states tid (+512 if NST==1024).
// ---------------------------------------------------------------------------
template<int APT, int NST>
__device__ void fsm_forward(const float* __restrict__ rowbase, int L,
    const uint2* __restrict__ arcs_g,
    const float* __restrict__ initv, const float* __restrict__ finalv,
    float* __restrict__ res,
    float* elh, float* beta_s, float* nbeta, unsigned* slot)
{
    const int tid = threadIdx.x;
    uint2 arc[APT];
    #pragma unroll
    for (int k = 0; k < APT; ++k) arc[k] = arcs_g[tid * APT + k];

    const bool st2 = (NST > 512);
    if (tid < NST) { beta_s[tid] = __expf(initv[tid]); nbeta[tid] = 0.f; }
    if (st2)       { beta_s[tid + 512] = __expf(initv[tid + 512]); nbeta[tid + 512] = 0.f; }
    float p[4];
    #pragma unroll
    for (int i = 0; i < 4; ++i) p[i] = rowbase[tid + 512 * i];
    #pragma unroll
    for (int i = 0; i < 4; ++i) elh[tid + 512 * i] = __expf(p[i]);
    if (tid == 0) slot[0] = 0u;
    float S = 0.f;
    float bown0 = 0.f, bown1 = 0.f;
    __syncthreads();

    for (int t = 0; t < L; ++t) {
        const bool pre = (t + 1 < L);
        // ---- Phase A: contributions (2 gathers + 2 mul per arc), run-summed
        if (pre) {
            const float* nb = rowbase + (size_t)(t + 1) * CC;
            #pragma unroll
            for (int i = 0; i < 4; ++i) p[i] = nb[tid + 512 * i];
        }
        if (tid == 0) slot[0] = 0u;   // safe: last read was C2(t-1), pre-barrier
        {
            float acc = 0.f;
            unsigned rd = arc[0].x >> 21;
            #pragma unroll
            for (int k = 0; k < APT; ++k) {
                const unsigned x = arc[k].x;
                acc += beta_s[x & 1023u] * __uint_as_float(arc[k].y)
                     * elh[(x >> 10) & 2047u];
                const unsigned nd = (k + 1 < APT) ? (arc[k + 1].x >> 21) : 0xffffffffu;
                if (nd != rd) { atomicAdd(&nbeta[rd], acc); acc = 0.f; rd = nd; }
            }
        }
        __syncthreads();
        // ---- Phase C1: collect own states, block max via shuffles + 1 ds_max/wave
        float n0 = 0.f, n1 = 0.f;
        if (tid < NST) { n0 = nbeta[tid]; nbeta[tid] = 0.f; }
        if (st2)       { n1 = nbeta[tid + 512]; nbeta[tid + 512] = 0.f; }
        if (pre) {
            #pragma unroll
            for (int i = 0; i < 4; ++i) elh[tid + 512 * i] = __expf(p[i]);
        }
        float wm = fmaxf(n0, n1);
        #pragma unroll
        for (int off = 32; off > 0; off >>= 1)
            wm = fmaxf(wm, __shfl_xor(wm, off));
        if ((tid & 63) == 0 && wm > 0.f)
            atomicMax(slot, __float_as_uint(wm));   // positive floats: uint order == float order
        __syncthreads();
        // ---- Phase C2: renormalize
        const float m = __uint_as_float(slot[0]);
        const float inv = 1.0f / m;
        S += __logf(m);
        bown0 = n0 * inv; bown1 = n1 * inv;
        if (tid < NST) beta_s[tid] = bown0;
        if (st2)       beta_s[tid + 512] = bown1;
        __syncthreads();
    }

    // res = S + log( sum_j beta[j] * exp(final[j]) )
    float v = 0.f;
    if (tid < NST) v += bown0 * __expf(finalv[tid]);
    if (st2)       v += bown1 * __expf(finalv[tid + 512]);
    #pragma unroll
    for (int off = 32; off > 0; off >>= 1) v += __shfl_xor(v, off);
    if ((tid & 63) == 0) elh[tid >> 6] = v;
    __syncthreads();
    if (tid == 0) {
        float s2 = 0.f;
        for (int i = 0; i < 8; ++i) s2 += elh[i];
        *res = S + __logf(s2);
    }
}

__global__ __launch_bounds__(512) void fwd_kernel(
    const float* __restrict__ est, const int* __restrict__ seqlen,
    const uint2* __restrict__ den_arcs,
    const float* __restrict__ den_init, const float* __restrict__ den_final,
    const uint2* __restrict__ num_arcs,
    const float* __restrict__ num_init, const float* __restrict__ num_final,
    float* __restrict__ res)
{
    __shared__ float elh[2048];
    __shared__ float beta_s[1024];
    __shared__ float nbeta[1024];
    __shared__ unsigned slot[1];
    const int bid = blockIdx.x;
    if (bid < 16) {
        const int s = bid >> 3, b = bid & 7;
        const float* rowbase = est + (size_t)(b * SS + s) * TT * CC;
        const int L = seqlen[b * SS + s];
        fsm_forward<32, ND>(rowbase, L, den_arcs, den_init, den_final,
                            &res[bid], elh, beta_s, nbeta, slot);
    } else {
        const int q = bid - 16;
        const int p = q >> 4, g = q & 15;
        const int s = g >> 3, b = g & 7;
        const int sp = p ? (1 - s) : s;
        const float* rowbase = est + (size_t)(b * SS + sp) * TT * CC;
        const int L = seqlen[b * SS + sp];
        fsm_forward<4, NN>(rowbase, L,
                           num_arcs + (size_t)g * AN,
                           num_init + (size_t)g * NN, num_final + (size_t)g * NN,
                           &res[16 + p * 16 + g], elh, beta_s, nbeta, slot);
    }
}

// res layout: [0..15] den (s*8+b), [16..31] num perm0, [32..47] num perm1
__global__ void finalize_kernel(const float* __restrict__ res, float* __restrict__ out)
{
    if (threadIdx.x == 0 && blockIdx.x == 0) {
        float loss = 0.f;
        for (int b = 0; b < BB; ++b) {
            const float den = res[b] + res[8 + b];
            const float n0  = res[16 + b] + res[16 + 8 + b];
            const float n1  = res[32 + b] + res[32 + 8 + b];
            const float nm  = fminf(n0, n1);
            loss += -(nm - den);
        }
        out[0] = loss;
    }
}

extern "C" void kernel_launch(void* const* d_in, const int* in_sizes, int n_in,
                              void* d_out, int out_size, void* d_ws, size_t ws_size,
                              hipStream_t stream)
{
    const float* est       = (const float*)d_in[0];
    const int*   seqlen    = (const int*)  d_in[1];
    const int*   den_src   = (const int*)  d_in[2];
    const int*   den_dst   = (const int*)  d_in[3];
    const int*   den_pdf   = (const int*)  d_in[4];
    const float* den_w     = (const float*)d_in[5];
    const float* den_init  = (const float*)d_in[6];
    const float* den_final = (const float*)d_in[7];
    const int*   num_src   = (const int*)  d_in[8];
    const int*   num_dst   = (const int*)  d_in[9];
    const int*   num_pdf   = (const int*)  d_in[10];
    const float* num_w     = (const float*)d_in[11];
    const float* num_init  = (const float*)d_in[12];
    const float* num_final = (const float*)d_in[13];

    char* ws = (char*)d_ws;
    uint2* den_arcs = (uint2*)(ws + 0);        // 131072 B
    uint2* num_arcs = (uint2*)(ws + 131072);   // 262144 B -> end 393216
    float* res      = (float*)(ws + 393216);   // 192 B

    prep_kernel<<<1, 1024, 0, stream>>>(den_src, den_dst, den_pdf, den_w,
                                        den_arcs, ND, AD);
    prep_kernel<<<16, 256, 0, stream>>>(num_src, num_dst, num_pdf, num_w,
                                        num_arcs, NN, AN);

    fwd_kernel<<<48, 512, 0, stream>>>(est, seqlen,
                                       den_arcs, den_init, den_final,
                                       num_arcs, num_init, num_final, res);

    finalize_kernel<<<1, 64, 0, stream>>>(res, (float*)d_out);
}